// Round 13
// baseline (27.144 us; speedup 1.0000x reference)
//
#include <hip/hip_runtime.h>
#include <math.h>

// B=4096, O=8, E=64, I=4, V=3, P=perm(8,3)=336
// unary_feats  (B,8,64)   f32
// binary_feats (B,8,8,64) f32
// rule_unary   (4,3,64)   f32  = [12][64]
// rule_binary  (4,3,3,64) f32  = [36][64]  (rule = i*9 + n*3 + m)
// out          (B,4)      f32  (col0=sel0+sel1, col1=sel2+sel3, col2=col3=0)
//
// v13: transposed-operand fused q-GEMM. For output col c=i*3+t at pair
// p=(x,y):  q[c][p] = dot(bf[x,y], rb_fwd[c]) + dot(bf[y,x], rb_rev[c])
// computed as ONE 4-MFMA accumulated chain per pos-tile: the rev half feeds
// the A-operand from the TRANSPOSED address (lane of pair (x,y) loads row
// y*8+x) so both halves share the C-layout. No bm, no combine, no phase 2.
// Separable terms ss[c=i*3+n][v] = dot(uf[v],ru)+dot(bf[v,v],rb_nn) via one
// 4-MFMA chain. Transposed/diag loads hit L1 (same lines as fwd loads).
// q/ss double-buffered across the wave's 2 elements -> zero guards, zero
// barriers (per-wave in-order LDS FIFO, validated v9-v12).
// score = q01[a][b] + q02[a][c] + q12[b][c] + ss0[a] + ss1[b] + ss2[c].

typedef __attribute__((ext_vector_type(8))) __bf16 bf16x8;
typedef __attribute__((ext_vector_type(4))) float  f32x4;

#define QS 68   // q row stride (floats)
#define SS 12   // ss row stride

__device__ inline bf16x8 cvt2(const float4 v0, const float4 v1) {
    bf16x8 r;
    r[0] = (__bf16)v0.x; r[1] = (__bf16)v0.y; r[2] = (__bf16)v0.z; r[3] = (__bf16)v0.w;
    r[4] = (__bf16)v1.x; r[5] = (__bf16)v1.y; r[6] = (__bf16)v1.z; r[7] = (__bf16)v1.w;
    return r;
}

__global__ __launch_bounds__(64, 2) void rule_learner_kernel(
    const float* __restrict__ uf,    // (B,8,64)
    const float* __restrict__ bfe,   // (B,8,8,64)
    const float* __restrict__ ru,    // [12][64]
    const float* __restrict__ rb,    // [36][64]
    float* __restrict__ out)         // (B,4)
{
    const int b0    = blockIdx.x * 2;
    const int lane  = threadIdx.x;   // one wave per block
    const int row16 = lane & 15;
    const int kg    = lane >> 4;
    const int kb    = kg * 8;

    __shared__ float q_s [2][12 * QS];  // 2 x 3264 B (double-buffered)
    __shared__ float ss_s[2][12 * SS];  // 2 x  576 B

    // ---- rule B-fragments, packed in-wave once (L1-hot f32) ----
    const int cc16  = row16 < 12 ? row16 : 11;      // clamped col
    const int ii    = cc16 / 3, tt = cc16 - ii * 3;
    const int rule1 = ii * 9 + (tt == 0 ? 1 : tt == 1 ? 2 : 5);  // (0,1)(0,2)(1,2)
    const int rule2 = ii * 9 + (tt == 0 ? 3 : tt == 1 ? 6 : 7);  // (1,0)(2,0)(2,1)
    const int ruled = ii * 9 + tt * 4;                            // (n,n)
    bf16x8 b1f0, b1f1, b2f0, b2f1, dbf0, dbf1, ruf0, ruf1;
    {
        const float* r1 = rb + rule1 * 64 + kb;
        b1f0 = cvt2(*(const float4*)r1,        *(const float4*)(r1 + 4));
        b1f1 = cvt2(*(const float4*)(r1 + 32), *(const float4*)(r1 + 36));
        const float* r2 = rb + rule2 * 64 + kb;
        b2f0 = cvt2(*(const float4*)r2,        *(const float4*)(r2 + 4));
        b2f1 = cvt2(*(const float4*)(r2 + 32), *(const float4*)(r2 + 36));
        const float* rd = rb + ruled * 64 + kb;
        dbf0 = cvt2(*(const float4*)rd,        *(const float4*)(rd + 4));
        dbf1 = cvt2(*(const float4*)(rd + 32), *(const float4*)(rd + 36));
        const float* rr = ru + cc16 * 64 + kb;
        ruf0 = cvt2(*(const float4*)rr,        *(const float4*)(rr + 4));
        ruf1 = cvt2(*(const float4*)(rr + 32), *(const float4*)(rr + 36));
    }

    // ---- elem0 fwd/unary/diag loads (rev rows loaded per-tile: same cache
    //      lines as fwd -> L1/MSHR-served, no extra HBM) ----
    float4 afF[4][4], uA[4], dA[4];
    {
        const float* base = bfe + (size_t)b0 * 4096;
        #pragma unroll
        for (int t = 0; t < 4; ++t) {
            const float* rp = base + (size_t)(t * 16 + row16) * 64 + kb;
            afF[t][0] = *(const float4*)rp;
            afF[t][1] = *(const float4*)(rp + 4);
            afF[t][2] = *(const float4*)(rp + 32);
            afF[t][3] = *(const float4*)(rp + 36);
        }
        const int v8c = row16 < 8 ? row16 : 7;
        const float* up = uf + (size_t)b0 * 512 + v8c * 64 + kb;
        uA[0] = *(const float4*)up;        uA[1] = *(const float4*)(up + 4);
        uA[2] = *(const float4*)(up + 32); uA[3] = *(const float4*)(up + 36);
        const float* dp = base + v8c * 576 + kb;   // bf[v][v]
        dA[0] = *(const float4*)dp;        dA[1] = *(const float4*)(dp + 4);
        dA[2] = *(const float4*)(dp + 32); dA[3] = *(const float4*)(dp + 36);
    }

    #pragma unroll
    for (int el = 0; el < 2; ++el) {
        const float* base = bfe + (size_t)(b0 + el) * 4096;

        // ---- phase 1: fused q-GEMM (fwd + transposed-rev in one chain) ----
        #pragma unroll
        for (int t = 0; t < 4; ++t) {
            // rev row for this lane's pair p = t*16+row16 = (x,y): row y*8+x
            const int x = t * 2 + (row16 >> 3);
            const int y = row16 & 7;
            const float* rp = base + (size_t)(y * 8 + x) * 64 + kb;
            const float4 r0 = *(const float4*)rp;
            const float4 r1 = *(const float4*)(rp + 4);
            const float4 r2 = *(const float4*)(rp + 32);
            const float4 r3 = *(const float4*)(rp + 36);
            const bf16x8 aF0 = cvt2(afF[t][0], afF[t][1]);
            const bf16x8 aF1 = cvt2(afF[t][2], afF[t][3]);
            const bf16x8 aR0 = cvt2(r0, r1);
            const bf16x8 aR1 = cvt2(r2, r3);
            f32x4 acc = {0.f, 0.f, 0.f, 0.f};
            acc = __builtin_amdgcn_mfma_f32_16x16x32_bf16(aF0, b1f0, acc, 0, 0, 0);
            acc = __builtin_amdgcn_mfma_f32_16x16x32_bf16(aF1, b1f1, acc, 0, 0, 0);
            acc = __builtin_amdgcn_mfma_f32_16x16x32_bf16(aR0, b2f0, acc, 0, 0, 0);
            acc = __builtin_amdgcn_mfma_f32_16x16x32_bf16(aR1, b2f1, acc, 0, 0, 0);
            // C: col = lane&15 (rule col c), rows(pairs) = t*16 + kg*4 + r
            if (row16 < 12)
                *(float4*)&q_s[el][row16 * QS + t * 16 + kg * 4] = *(float4*)&acc;
        }
        // separable: ss[c=i*3+n][v] = dot(uf[v],ru_c) + dot(bf[v,v],rb_nn)
        {
            const bf16x8 ua0 = cvt2(uA[0], uA[1]);
            const bf16x8 ua1 = cvt2(uA[2], uA[3]);
            const bf16x8 da0 = cvt2(dA[0], dA[1]);
            const bf16x8 da1 = cvt2(dA[2], dA[3]);
            f32x4 zs = {0.f, 0.f, 0.f, 0.f};
            zs = __builtin_amdgcn_mfma_f32_16x16x32_bf16(ua0, ruf0, zs, 0, 0, 0);
            zs = __builtin_amdgcn_mfma_f32_16x16x32_bf16(ua1, ruf1, zs, 0, 0, 0);
            zs = __builtin_amdgcn_mfma_f32_16x16x32_bf16(da0, dbf0, zs, 0, 0, 0);
            zs = __builtin_amdgcn_mfma_f32_16x16x32_bf16(da1, dbf1, zs, 0, 0, 0);
            if (row16 < 12 && kg < 2)     // valid objects v = kg*4+r < 8
                *(float4*)&ss_s[el][row16 * SS + kg * 4] = *(float4*)&zs;
        }

        // ---- prefetch elem1 fwd/unary/diag (rev waits for these to land,
        //      loaded L1-hot at elem1's phase 1) ----
        if (el == 0) {
            const float* nb = bfe + (size_t)(b0 + 1) * 4096;
            #pragma unroll
            for (int t = 0; t < 4; ++t) {
                const float* rp = nb + (size_t)(t * 16 + row16) * 64 + kb;
                afF[t][0] = *(const float4*)rp;
                afF[t][1] = *(const float4*)(rp + 4);
                afF[t][2] = *(const float4*)(rp + 32);
                afF[t][3] = *(const float4*)(rp + 36);
            }
            const int v8c = row16 < 8 ? row16 : 7;
            const float* up = uf + (size_t)(b0 + 1) * 512 + v8c * 64 + kb;
            uA[0] = *(const float4*)up;        uA[1] = *(const float4*)(up + 4);
            uA[2] = *(const float4*)(up + 32); uA[3] = *(const float4*)(up + 36);
            const float* dp = nb + v8c * 576 + kb;
            dA[0] = *(const float4*)dp;        dA[1] = *(const float4*)(dp + 4);
            dA[2] = *(const float4*)(dp + 32); dA[3] = *(const float4*)(dp + 36);
        }

        // ---- phase 3: lane = ordered pair (a,bb), sweep cc for all 4 i ----
        float mn[4] = {INFINITY, INFINITY, INFINITY, INFINITY};
        if (lane < 56) {
            const int a  = lane / 7;
            const int o  = lane - a * 7;
            const int bb = o + (o >= a);
            #pragma unroll
            for (int i = 0; i < 4; ++i) {
                const float bs = q_s[el][(i * 3 + 0) * QS + a * 8 + bb]
                               + ss_s[el][(i * 3 + 0) * SS + a]
                               + ss_s[el][(i * 3 + 1) * SS + bb];
                const float4 c0 = *(const float4*)&q_s[el][(i * 3 + 1) * QS + a * 8];
                const float4 c1 = *(const float4*)&q_s[el][(i * 3 + 1) * QS + a * 8 + 4];
                const float4 d0 = *(const float4*)&q_s[el][(i * 3 + 2) * QS + bb * 8];
                const float4 d1 = *(const float4*)&q_s[el][(i * 3 + 2) * QS + bb * 8 + 4];
                const float4 e0 = *(const float4*)&ss_s[el][(i * 3 + 2) * SS];      // uniform
                const float4 e1 = *(const float4*)&ss_s[el][(i * 3 + 2) * SS + 4];  // broadcast
                float vv[8];
                vv[0] = c0.x + d0.x + e0.x; vv[1] = c0.y + d0.y + e0.y;
                vv[2] = c0.z + d0.z + e0.z; vv[3] = c0.w + d0.w + e0.w;
                vv[4] = c1.x + d1.x + e1.x; vv[5] = c1.y + d1.y + e1.y;
                vv[6] = c1.z + d1.z + e1.z; vv[7] = c1.w + d1.w + e1.w;
                float m = INFINITY;
                #pragma unroll
                for (int cc = 0; cc < 8; ++cc) {
                    const float s = (cc == a || cc == bb) ? INFINITY : (bs + vv[cc]);
                    m = fminf(m, s);
                }
                mn[i] = m;
            }
        }
        #pragma unroll
        for (int s = 1; s <= 32; s <<= 1) {
            #pragma unroll
            for (int i = 0; i < 4; ++i) mn[i] = fminf(mn[i], __shfl_xor(mn[i], s));
        }
        if (lane == 0) {
            const float mx = fmaxf(fmaxf(mn[0], mn[1]), fmaxf(mn[2], mn[3]));
            const float e0 = expf(mn[0] - mx), e1 = expf(mn[1] - mx);
            const float e2 = expf(mn[2] - mx), e3 = expf(mn[3] - mx);
            const float inv = 1.f / (e0 + e1 + e2 + e3);
            *(float4*)(out + (size_t)(b0 + el) * 4) =
                make_float4((e0 + e1) * inv, (e2 + e3) * inv, 0.f, 0.f);
        }
        // no guard: q/ss double-buffered; per-wave LDS FIFO is in-order.
    }
}

extern "C" void kernel_launch(void* const* d_in, const int* in_sizes, int n_in,
                              void* d_out, int out_size, void* d_ws, size_t ws_size,
                              hipStream_t stream) {
    const float* uf = (const float*)d_in[0];   // (4096,8,64)
    const float* bf = (const float*)d_in[1];   // (4096,8,8,64)
    const float* ru = (const float*)d_in[2];   // (4,3,64)
    const float* rb = (const float*)d_in[3];   // (4,3,3,64)
    float* out = (float*)d_out;                // (4096,4)

    const int B = in_sizes[0] / (8 * 64);      // 4096
    rule_learner_kernel<<<B / 2, 64, 0, stream>>>(uf, bf, ru, rb, out);
}

// Round 14
// 21.164 us; speedup vs baseline: 1.2825x; 1.2825x over previous
//
#include <hip/hip_runtime.h>
#include <math.h>

// B=4096, O=8, E=64, I=4, V=3, P=perm(8,3)=336
// unary_feats  (B,8,64)   f32
// binary_feats (B,8,8,64) f32
// rule_unary   (4,3,64)   f32  = [12][64]
// rule_binary  (4,3,3,64) f32  = [36][64]  (rule = i*9 + n*3 + m)
// out          (B,4)      f32  (col0=sel0+sel1, col1=sel2+sel3, col2=col3=0)
//
// v14 = v11 structure (wave-autonomous, 2 elem/wave, zero barriers, single
// dispatch, elem1 prefetch after phase 1) with the LDS diet:
//  - MFMA operands SWAPPED (A=rules, B=features) -> C = [pos][slot]; each
//    C-frag stores as ONE b128 into bm_t[pos][slot].
//  - slot permutation (set at rule-pack time, nibble LUT) groups the rules
//    phase 2 reads at the same row:  per i (12 slots, c=i*12+s):
//      s0..2 = r1,r2,r5   read @ row x8y (b128, slot s3=r0 junk there)
//      s3    = r0         read @ row x8x (b32)
//      s4..6 = r3,r6,r7   read @ row y8x (b128, s7 pad)
//      s8,9  = r4,r8      read @ row y8y (b64)
//  - phase 2 computes q01 (kept IN REGISTER, p-space), q02 (+um2+r8 folded),
//    q12; phase 3 per i = just 4x ds_read_b128 (q02 row a, q12 row b).
// score(i;a,b,c) = q01r[a,b] + q02[a][c] + q12[b][c].

typedef __attribute__((ext_vector_type(8))) __bf16 bf16x8;
typedef __attribute__((ext_vector_type(4))) float  f32x4;

#define BMS2 52   // bm_t row stride (floats): 64 rows x 48 slots + pad
#define QS2  68   // q_s row stride (8 rows: [i*2+{0,1}][pair])
#define SSU  12   // um row stride

__device__ inline bf16x8 cvt2(const float4 v0, const float4 v1) {
    bf16x8 r;
    r[0] = (__bf16)v0.x; r[1] = (__bf16)v0.y; r[2] = (__bf16)v0.z; r[3] = (__bf16)v0.w;
    r[4] = (__bf16)v1.x; r[5] = (__bf16)v1.y; r[6] = (__bf16)v1.z; r[7] = (__bf16)v1.w;
    return r;
}

__global__ __launch_bounds__(64, 2) void rule_learner_kernel(
    const float* __restrict__ uf,    // (B,8,64)
    const float* __restrict__ bfe,   // (B,8,8,64)
    const float* __restrict__ ru,    // [12][64]
    const float* __restrict__ rb,    // [36][64]
    float* __restrict__ out)         // (B,4)
{
    const int b0    = blockIdx.x * 2;
    const int lane  = threadIdx.x;   // one wave per block
    const int row16 = lane & 15;
    const int kg    = lane >> 4;
    const int kb    = kg * 8;
    const int x     = lane >> 3;     // pair (x,y): p = lane
    const int y     = lane & 7;
    const int rev   = y * 8 + x;

    __shared__ float bm_t[64 * BMS2];  // 13312 B  [pos][slot]
    __shared__ float q_s [8 * QS2];    //  2176 B  [i*2+t][pair]
    __shared__ float um  [12 * SSU];   //   576 B  [i*3+n][v]

    // ---- rule A-fragments (packed once per wave, L1-hot f32) ----
    // slot c = T*16+row16; i=c/12, s=c%12; rule = i*9 + nib(s)
    // nib: s->m  {1,2,5,0,3,6,7,0,4,8,0,0}
    bf16x8 raf[6];
    #pragma unroll
    for (int T = 0; T < 3; ++T) {
        const int c = T * 16 + row16;
        const int i = c / 12, s = c - i * 12;
        const int m = (int)((0x008407630521ull >> (4 * s)) & 15ull);
        const float* rp = rb + (i * 9 + m) * 64 + kb;
        raf[T * 2 + 0] = cvt2(*(const float4*)rp,        *(const float4*)(rp + 4));
        raf[T * 2 + 1] = cvt2(*(const float4*)(rp + 32), *(const float4*)(rp + 36));
    }
    bf16x8 ruf0, ruf1;
    {
        const float* rr = ru + (row16 < 12 ? row16 : 11) * 64 + kb;
        ruf0 = cvt2(*(const float4*)rr,        *(const float4*)(rr + 4));
        ruf1 = cvt2(*(const float4*)(rr + 32), *(const float4*)(rr + 36));
    }

    // ---- elem0 feature loads ----
    float4 af[4][4], uA[4];
    {
        const float* base = bfe + (size_t)b0 * 4096;
        #pragma unroll
        for (int t = 0; t < 4; ++t) {
            const float* rp = base + (size_t)(t * 16 + row16) * 64 + kb;
            af[t][0] = *(const float4*)rp;
            af[t][1] = *(const float4*)(rp + 4);
            af[t][2] = *(const float4*)(rp + 32);
            af[t][3] = *(const float4*)(rp + 36);
        }
        const float* up = uf + (size_t)b0 * 512 + (row16 < 8 ? row16 : 7) * 64 + kb;
        uA[0] = *(const float4*)up;        uA[1] = *(const float4*)(up + 4);
        uA[2] = *(const float4*)(up + 32); uA[3] = *(const float4*)(up + 36);
    }

    #pragma unroll
    for (int el = 0; el < 2; ++el) {
        // ---- phase 1: A-swapped MFMA, C = [pos][slot], 1 b128 store each ----
        #pragma unroll
        for (int P = 0; P < 4; ++P) {
            const bf16x8 fb0 = cvt2(af[P][0], af[P][1]);   // feats as B, k 0..31
            const bf16x8 fb1 = cvt2(af[P][2], af[P][3]);   // k 32..63
            #pragma unroll
            for (int T = 0; T < 3; ++T) {
                f32x4 acc = {0.f, 0.f, 0.f, 0.f};
                acc = __builtin_amdgcn_mfma_f32_16x16x32_bf16(raf[T * 2 + 0], fb0, acc, 0, 0, 0);
                acc = __builtin_amdgcn_mfma_f32_16x16x32_bf16(raf[T * 2 + 1], fb1, acc, 0, 0, 0);
                // C: col(lane&15)=pos-in-tile, row(kg*4+r)=slot-in-tile
                *(float4*)&bm_t[(P * 16 + row16) * BMS2 + T * 16 + kg * 4] = *(float4*)&acc;
            }
        }
        {   // unary: C[col=ruleu][row=v]  (same as v11)
            const bf16x8 ua0 = cvt2(uA[0], uA[1]);
            const bf16x8 ua1 = cvt2(uA[2], uA[3]);
            f32x4 acc = {0.f, 0.f, 0.f, 0.f};
            acc = __builtin_amdgcn_mfma_f32_16x16x32_bf16(ua0, ruf0, acc, 0, 0, 0);
            acc = __builtin_amdgcn_mfma_f32_16x16x32_bf16(ua1, ruf1, acc, 0, 0, 0);
            if (row16 < 12 && kg < 2)
                *(float4*)&um[row16 * SSU + kg * 4] = *(float4*)&acc;
        }

        // ---- issue elem1 loads NOW (latency hides under phases 2-3) ----
        if (el == 0) {
            const float* nb = bfe + (size_t)(b0 + 1) * 4096;
            #pragma unroll
            for (int t = 0; t < 4; ++t) {
                const float* rp = nb + (size_t)(t * 16 + row16) * 64 + kb;
                af[t][0] = *(const float4*)rp;
                af[t][1] = *(const float4*)(rp + 4);
                af[t][2] = *(const float4*)(rp + 32);
                af[t][3] = *(const float4*)(rp + 36);
            }
            const float* up = uf + (size_t)(b0 + 1) * 512
                            + (row16 < 8 ? row16 : 7) * 64 + kb;
            uA[0] = *(const float4*)up;        uA[1] = *(const float4*)(up + 4);
            uA[2] = *(const float4*)(up + 32); uA[3] = *(const float4*)(up + 36);
        }

        // ---- phase 2: vector reads from bm_t; q01 stays in registers ----
        float q01r[4];
        #pragma unroll
        for (int i = 0; i < 4; ++i) {
            const float4 F = *(const float4*)&bm_t[lane * BMS2 + i * 12];      // r1,r2,r5,-
            const float4 R = *(const float4*)&bm_t[rev  * BMS2 + i * 12 + 4];  // r3,r6,r7,-
            const float2 D = *(const float2*)&bm_t[(y * 9) * BMS2 + i * 12 + 8]; // r4,r8
            const float  z = bm_t[(x * 9) * BMS2 + i * 12 + 3];                // r0
            const float u0 = um[(i * 3 + 0) * SSU + x];
            const float u1 = um[(i * 3 + 1) * SSU + y];
            const float u2 = um[(i * 3 + 2) * SSU + y];
            q01r[i] = F.x + R.x + z + D.x + u0 + u1;
            q_s[(i * 2 + 0) * QS2 + lane] = F.y + R.y + D.y + u2;  // q02 (+um2+r8)
            q_s[(i * 2 + 1) * QS2 + lane] = F.z + R.z;             // q12
        }

        // ---- phase 3 (p-space): lane = pair (a=x, b=y), sweep cc ----
        float mn[4] = {INFINITY, INFINITY, INFINITY, INFINITY};
        if (x != y) {
            #pragma unroll
            for (int i = 0; i < 4; ++i) {
                const float  bs = q01r[i];
                const float4 c0 = *(const float4*)&q_s[(i * 2 + 0) * QS2 + x * 8];
                const float4 c1 = *(const float4*)&q_s[(i * 2 + 0) * QS2 + x * 8 + 4];
                const float4 d0 = *(const float4*)&q_s[(i * 2 + 1) * QS2 + y * 8];
                const float4 d1 = *(const float4*)&q_s[(i * 2 + 1) * QS2 + y * 8 + 4];
                float vv[8];
                vv[0] = c0.x + d0.x; vv[1] = c0.y + d0.y;
                vv[2] = c0.z + d0.z; vv[3] = c0.w + d0.w;
                vv[4] = c1.x + d1.x; vv[5] = c1.y + d1.y;
                vv[6] = c1.z + d1.z; vv[7] = c1.w + d1.w;
                float m = INFINITY;
                #pragma unroll
                for (int cc = 0; cc < 8; ++cc) {
                    const float s = (cc == x || cc == y) ? INFINITY : (bs + vv[cc]);
                    m = fminf(m, s);
                }
                mn[i] = m;
            }
        }
        #pragma unroll
        for (int s = 1; s <= 32; s <<= 1) {
            #pragma unroll
            for (int i = 0; i < 4; ++i) mn[i] = fminf(mn[i], __shfl_xor(mn[i], s));
        }
        if (lane == 0) {
            const float mx = fmaxf(fmaxf(mn[0], mn[1]), fmaxf(mn[2], mn[3]));
            const float e0 = expf(mn[0] - mx), e1 = expf(mn[1] - mx);
            const float e2 = expf(mn[2] - mx), e3 = expf(mn[3] - mx);
            const float inv = 1.f / (e0 + e1 + e2 + e3);
            *(float4*)(out + (size_t)(b0 + el) * 4) =
                make_float4((e0 + e1) * inv, (e2 + e3) * inv, 0.f, 0.f);
        }

        // ---- LDS reuse guard (WAR) between elements: DS-only wait keeps the
        // elem1 global prefetch in flight; sched_barrier stops hoisting. ----
        if (el == 0) {
            asm volatile("s_waitcnt lgkmcnt(0)" ::: "memory");
            __builtin_amdgcn_sched_barrier(0);
        }
    }
}

extern "C" void kernel_launch(void* const* d_in, const int* in_sizes, int n_in,
                              void* d_out, int out_size, void* d_ws, size_t ws_size,
                              hipStream_t stream) {
    const float* uf = (const float*)d_in[0];   // (4096,8,64)
    const float* bf = (const float*)d_in[1];   // (4096,8,8,64)
    const float* ru = (const float*)d_in[2];   // (4,3,64)
    const float* rb = (const float*)d_in[3];   // (4,3,3,64)
    float* out = (float*)d_out;                // (4096,4)

    const int B = in_sizes[0] / (8 * 64);      // 4096
    rule_learner_kernel<<<B / 2, 64, 0, stream>>>(uf, bf, ru, rb, out);
}